// Round 8
// baseline (685.984 us; speedup 1.0000x reference)
//
#include <hip/hip_runtime.h>
#include <hip/hip_fp16.h>

#define DIM 64
#define NG  16          // num graphs
#define CPG 16          // edge chunks per graph (hist/fill parallelism)
#define NPG 4096        // nodes per graph
#define LSTR 68
#define HISTB (NG*CPG)  // 256 hist/fill blocks
#define GGN 64          // dst nodes per fused gather+gemm block (8-lane groups)

// ---------------------------------------------------------------------------
// kA: per-chunk LDS degree histograms. 256 blocks.
// ---------------------------------------------------------------------------
__global__ __launch_bounds__(256) void kA_hist(
    const int* __restrict__ src, const int* __restrict__ dst,
    int* __restrict__ hsub, int* __restrict__ dsub, int chunk, int npg)
{
    __shared__ int hs[NPG], hd[NPG];
    const int blk = blockIdx.x;
    const int g = blk / CPG;
    const int t = threadIdx.x;
    const int ebase = blk * chunk;
    const int nbase = g * npg;
    for (int i = t; i < npg; i += 256) { hs[i] = 0; hd[i] = 0; }
    __syncthreads();
    for (int e = t; e < chunk; e += 256) {
        atomicAdd(&hs[src[ebase + e] - nbase], 1);
        atomicAdd(&hd[dst[ebase + e] - nbase], 1);
    }
    __syncthreads();
    for (int i = t; i < npg; i += 256) {
        hsub[blk * npg + i] = hs[i];
        dsub[blk * npg + i] = hd[i];
    }
}

// ---------------------------------------------------------------------------
// k2a: full-GPU chunk reduction. One thread per node (256 blocks): sum the
// CPG sub-hists -> ns/nd/degd. Fully coalesced. (R7's k2 did this with 16
// blocks = 6% of CUs -- the hidden serial whale.)
// ---------------------------------------------------------------------------
__global__ __launch_bounds__(256) void k2a_norms(
    const int* __restrict__ hsub, const int* __restrict__ dsub,
    float* __restrict__ ns, float* __restrict__ nd, int* __restrict__ degd,
    int npg)
{
    const int node = blockIdx.x * 256 + threadIdx.x;
    const int g = node / npg;
    const int i = node - g * npg;
    int sd = 0, dd = 0;
#pragma unroll
    for (int k = 0; k < CPG; ++k) {
        sd += hsub[(g * CPG + k) * npg + i];
        dd += dsub[(g * CPG + k) * npg + i];
    }
    ns[node] = sd > 0 ? rsqrtf((float)sd) : 0.0f;
    nd[node] = dd > 0 ? rsqrtf((float)dd) : 0.0f;
    degd[node] = dd;
}

// ---------------------------------------------------------------------------
// k2b: per-graph exclusive scan of in-degrees -> rowptr. 16 blocks but now
// reads only 256 KB (degd) instead of 16 MB.
// ---------------------------------------------------------------------------
__global__ __launch_bounds__(1024) void k2b_scan(
    const int* __restrict__ degd, int* __restrict__ rowptr,
    int epg, int npg, int N, int E)
{
    __shared__ int wsum[16];
    const int g = blockIdx.x;
    const int t = threadIdx.x;
    const int nbase = g * npg;
    const int ebase = g * epg;
    const int i0 = 4 * t;
    const int4 d = *(const int4*)&degd[nbase + i0];
    int s4 = d.x + d.y + d.z + d.w;
    const int lane = t & 63, wid = t >> 6;
    int v = s4;
#pragma unroll
    for (int off = 1; off < 64; off <<= 1) {
        int u = __shfl_up(v, off, 64);
        if (lane >= off) v += u;
    }
    if (lane == 63) wsum[wid] = v;
    __syncthreads();
    if (t < 16) {
        int w = wsum[t];
#pragma unroll
        for (int off = 1; off < 16; off <<= 1) {
            int u = __shfl_up(w, off, 16);
            if (t >= off) w += u;
        }
        wsum[t] = w;
    }
    __syncthreads();
    int incl = v + (wid > 0 ? wsum[wid - 1] : 0);
    int c = ebase + incl - s4;
    rowptr[nbase + i0    ] = c; c += d.x;
    rowptr[nbase + i0 + 1] = c; c += d.y;
    rowptr[nbase + i0 + 2] = c; c += d.z;
    rowptr[nbase + i0 + 3] = c;
    if (g == 0 && t == 0) rowptr[N] = E;
}

// ---------------------------------------------------------------------------
// k2c: full-GPU cursor rewrite. One thread per node: in-place prefix of the
// CPG sub-counts -> per-chunk ABSOLUTE cursor starts. Coalesced per k.
// ---------------------------------------------------------------------------
__global__ __launch_bounds__(256) void k2c_cursors(
    int* __restrict__ dsub, const int* __restrict__ rowptr, int npg)
{
    const int node = blockIdx.x * 256 + threadIdx.x;
    const int g = node / npg;
    const int i = node - g * npg;
    int cc = rowptr[node];
#pragma unroll
    for (int k = 0; k < CPG; ++k) {
        int* p = &dsub[(g * CPG + k) * npg + i];
        int old = *p; *p = cc; cc += old;
    }
}

// ---------------------------------------------------------------------------
// kC: fused. Blocks [0,HISTB): fill ssrc via LDS cursors (stable counting
// sort). Blocks [HISTB, HISTB+N/32): hF = fp16( (ns ⊙ x) @ W1 ).
// ---------------------------------------------------------------------------
__global__ __launch_bounds__(256) void kC_gemm_fill(
    const int* __restrict__ src, const int* __restrict__ dst,
    const int* __restrict__ dsub, int* __restrict__ ssrc, int chunk, int npg,
    const float* __restrict__ x, const float* __restrict__ W1,
    const float* __restrict__ ns, __half* __restrict__ hF, int swiz)
{
    __shared__ float smem[64 * LSTR + 32 * LSTR];   // 26 KB (fill uses 16 KB)
    const int tid = threadIdx.x;
    if ((int)blockIdx.x < HISTB) {
        int* cur = (int*)smem;
        const int blk = blockIdx.x;
        const int g = blk / CPG;
        const int ebase = blk * chunk;
        const int nbase = g * npg;
        for (int i = tid; i < npg; i += 256) cur[i] = dsub[blk * npg + i];
        __syncthreads();
        for (int e = tid; e < chunk; e += 256) {
            int s = src[ebase + e];
            int d = dst[ebase + e] - nbase;
            int pos = atomicAdd(&cur[d], 1);
            ssrc[pos] = s;
        }
    } else {
        float* Wt = smem;                    // Wt[c][k], 64*LSTR
        float* xs = Wt + 64 * LSTR;          // xs[r][k], 32*LSTR
        int blk = blockIdx.x - HISTB;
        if (swiz) {                          // 2048 blocks: 16 graphs x 128
            int xg = blk & 7;
            int j = blk >> 3;
            int g = xg + ((j >> 7) << 3);
            blk = (g << 7) + (j & 127);
        }
        const int row0 = blk * 32;
        for (int i = tid; i < 64 * 64; i += 256) {
            int k = i >> 6, c = i & 63;
            Wt[c * LSTR + k] = W1[i];
        }
        for (int i = tid; i < 32 * 64; i += 256) {
            int r = i >> 6, c = i & 63;
            int row = row0 + r;
            xs[r * LSTR + c] = x[(size_t)row * 64 + c] * ns[row];
        }
        __syncthreads();
        const int c0 = tid & 31;
        const int r0 = tid >> 5;
        float acc[4][2] = {};
#pragma unroll
        for (int k = 0; k < 64; k += 4) {
            float4 w0 = *(const float4*)&Wt[(c0     ) * LSTR + k];
            float4 w1 = *(const float4*)&Wt[(c0 + 32) * LSTR + k];
#pragma unroll
            for (int rr = 0; rr < 4; ++rr) {
                float4 xv = *(const float4*)&xs[(r0 + 8 * rr) * LSTR + k];
                acc[rr][0] += xv.x * w0.x + xv.y * w0.y + xv.z * w0.z + xv.w * w0.w;
                acc[rr][1] += xv.x * w1.x + xv.y * w1.y + xv.z * w1.z + xv.w * w1.w;
            }
        }
#pragma unroll
        for (int rr = 0; rr < 4; ++rr) {
            int row = row0 + r0 + 8 * rr;
            hF[(size_t)row * 64 + c0     ] = __float2half_rn(acc[rr][0]);
            hF[(size_t)row * 64 + c0 + 32] = __float2half_rn(acc[rr][1]);
        }
    }
}

// ---------------------------------------------------------------------------
// Gather core, uint4 / 8-lane groups: lane sub owns dims [sub*8, sub*8+8)
// = one uint4 (16B) per edge -> half the VMEM instructions per byte vs the
// uint2/16-lane core, same 128B/row coalescing. Dual-node stream for
// within-iteration MLP + idx-only cross-iteration carry (R4 lesson: carried
// DATA + launch_bounds cap spilled; R5: carried data alone re-serialized).
// ---------------------------------------------------------------------------
__device__ __forceinline__ void acc_u4(float4& A, float4& B, uint4 u)
{
    __half2 h0 = *(__half2*)&u.x;
    __half2 h1 = *(__half2*)&u.y;
    __half2 h2 = *(__half2*)&u.z;
    __half2 h3 = *(__half2*)&u.w;
    float2 f0 = __half22float2(h0), f1 = __half22float2(h1);
    float2 f2 = __half22float2(h2), f3 = __half22float2(h3);
    A.x += f0.x; A.y += f0.y; A.z += f1.x; A.w += f1.y;
    B.x += f2.x; B.y += f2.y; B.z += f3.x; B.w += f3.y;
}

__device__ __forceinline__ void acc_u4s(float4& A, float4& B, uint4 u, float s)
{
    __half2 h0 = *(__half2*)&u.x;
    __half2 h1 = *(__half2*)&u.y;
    __half2 h2 = *(__half2*)&u.z;
    __half2 h3 = *(__half2*)&u.w;
    float2 f0 = __half22float2(h0), f1 = __half22float2(h1);
    float2 f2 = __half22float2(h2), f3 = __half22float2(h3);
    A.x += s * f0.x; A.y += s * f0.y; A.z += s * f1.x; A.w += s * f1.y;
    B.x += s * f2.x; B.y += s * f2.y; B.z += s * f3.x; B.w += s * f3.y;
}

// single-stream remainder: full 8-batches then predicated tail (<8)
__device__ __forceinline__ void gather_rest(
    const __half* __restrict__ h, const int* __restrict__ ssrc,
    int j, int end, int sub, float4& A, float4& B)
{
    const size_t off = (size_t)sub * 8;
    const int last = end - 8;
    while (j <= last) {
        int s0 = ssrc[j+0], s1 = ssrc[j+1], s2 = ssrc[j+2], s3 = ssrc[j+3];
        int s4 = ssrc[j+4], s5 = ssrc[j+5], s6 = ssrc[j+6], s7 = ssrc[j+7];
        uint4 u0 = *(const uint4*)(h + (size_t)s0 * 64 + off);
        uint4 u1 = *(const uint4*)(h + (size_t)s1 * 64 + off);
        uint4 u2 = *(const uint4*)(h + (size_t)s2 * 64 + off);
        uint4 u3 = *(const uint4*)(h + (size_t)s3 * 64 + off);
        uint4 u4 = *(const uint4*)(h + (size_t)s4 * 64 + off);
        uint4 u5 = *(const uint4*)(h + (size_t)s5 * 64 + off);
        uint4 u6 = *(const uint4*)(h + (size_t)s6 * 64 + off);
        uint4 u7 = *(const uint4*)(h + (size_t)s7 * 64 + off);
        acc_u4(A, B, u0); acc_u4(A, B, u1); acc_u4(A, B, u2); acc_u4(A, B, u3);
        acc_u4(A, B, u4); acc_u4(A, B, u5); acc_u4(A, B, u6); acc_u4(A, B, u7);
        j += 8;
    }
    int rem = end - j;      // 0..7
    if (rem > 0) {
#pragma unroll
        for (int q = 0; q < 4; ++q) {
            int jj = j + (q < rem ? q : rem - 1);    // clamped: always valid
            int s = ssrc[jj];
            uint4 u = *(const uint4*)(h + (size_t)s * 64 + off);
            acc_u4s(A, B, u, (q < rem) ? 1.0f : 0.0f);
        }
        if (rem > 4) {
#pragma unroll
            for (int q = 4; q < 8; ++q) {
                int jj = j + (q < rem ? q : rem - 1);
                int s = ssrc[jj];
                uint4 u = *(const uint4*)(h + (size_t)s * 64 + off);
                acc_u4s(A, B, u, (q < rem) ? 1.0f : 0.0f);
            }
        }
    }
}

__device__ __forceinline__ void gather_node2(
    const __half* __restrict__ h, const int* __restrict__ ssrc,
    int begA, int endA, int begB, int endB, int sub,
    float4& accA0, float4& accA1, float4& accB0, float4& accB1)
{
    const size_t off = (size_t)sub * 8;
    int jA = begA, jB = begB;
    const int lastA = endA - 8, lastB = endB - 8;
    if (jA <= lastA && jB <= lastB) {
        int a0 = ssrc[jA+0], a1 = ssrc[jA+1], a2 = ssrc[jA+2], a3 = ssrc[jA+3];
        int a4 = ssrc[jA+4], a5 = ssrc[jA+5], a6 = ssrc[jA+6], a7 = ssrc[jA+7];
        int b0 = ssrc[jB+0], b1 = ssrc[jB+1], b2 = ssrc[jB+2], b3 = ssrc[jB+3];
        int b4 = ssrc[jB+4], b5 = ssrc[jB+5], b6 = ssrc[jB+6], b7 = ssrc[jB+7];
        for (;;) {
            uint4 uA0 = *(const uint4*)(h + (size_t)a0 * 64 + off);
            uint4 uA1 = *(const uint4*)(h + (size_t)a1 * 64 + off);
            uint4 uA2 = *(const uint4*)(h + (size_t)a2 * 64 + off);
            uint4 uA3 = *(const uint4*)(h + (size_t)a3 * 64 + off);
            uint4 uA4 = *(const uint4*)(h + (size_t)a4 * 64 + off);
            uint4 uA5 = *(const uint4*)(h + (size_t)a5 * 64 + off);
            uint4 uA6 = *(const uint4*)(h + (size_t)a6 * 64 + off);
            uint4 uA7 = *(const uint4*)(h + (size_t)a7 * 64 + off);
            uint4 uB0 = *(const uint4*)(h + (size_t)b0 * 64 + off);
            uint4 uB1 = *(const uint4*)(h + (size_t)b1 * 64 + off);
            uint4 uB2 = *(const uint4*)(h + (size_t)b2 * 64 + off);
            uint4 uB3 = *(const uint4*)(h + (size_t)b3 * 64 + off);
            uint4 uB4 = *(const uint4*)(h + (size_t)b4 * 64 + off);
            uint4 uB5 = *(const uint4*)(h + (size_t)b5 * 64 + off);
            uint4 uB6 = *(const uint4*)(h + (size_t)b6 * 64 + off);
            uint4 uB7 = *(const uint4*)(h + (size_t)b7 * 64 + off);
            jA += 8; jB += 8;
            bool more = (jA <= lastA) && (jB <= lastB);
            int pA = more ? jA : begA;
            int pB = more ? jB : begB;
            int na0 = ssrc[pA+0], na1 = ssrc[pA+1], na2 = ssrc[pA+2], na3 = ssrc[pA+3];
            int na4 = ssrc[pA+4], na5 = ssrc[pA+5], na6 = ssrc[pA+6], na7 = ssrc[pA+7];
            int nb0 = ssrc[pB+0], nb1 = ssrc[pB+1], nb2 = ssrc[pB+2], nb3 = ssrc[pB+3];
            int nb4 = ssrc[pB+4], nb5 = ssrc[pB+5], nb6 = ssrc[pB+6], nb7 = ssrc[pB+7];
            acc_u4(accA0, accA1, uA0); acc_u4(accA0, accA1, uA1);
            acc_u4(accA0, accA1, uA2); acc_u4(accA0, accA1, uA3);
            acc_u4(accA0, accA1, uA4); acc_u4(accA0, accA1, uA5);
            acc_u4(accA0, accA1, uA6); acc_u4(accA0, accA1, uA7);
            acc_u4(accB0, accB1, uB0); acc_u4(accB0, accB1, uB1);
            acc_u4(accB0, accB1, uB2); acc_u4(accB0, accB1, uB3);
            acc_u4(accB0, accB1, uB4); acc_u4(accB0, accB1, uB5);
            acc_u4(accB0, accB1, uB6); acc_u4(accB0, accB1, uB7);
            if (!more) break;
            a0 = na0; a1 = na1; a2 = na2; a3 = na3;
            a4 = na4; a5 = na5; a6 = na6; a7 = na7;
            b0 = nb0; b1 = nb1; b2 = nb2; b3 = nb3;
            b4 = nb4; b5 = nb5; b6 = nb6; b7 = nb7;
        }
    }
    gather_rest(h, ssrc, jA, endA, sub, accA0, accA1);
    gather_rest(h, ssrc, jB, endB, sub, accB0, accB1);
}

// ---------------------------------------------------------------------------
// Fused gather + next-layer GEMM (h pre-scaled by ns). Per dst node w:
//   acc = sum h[s];  u = acc*(nd*ns) + ns*bprev;  y = u @ W;  hout = fp16(y)
// 4 waves x 8 groups x 2 nodes = 64 nodes/block. Epilogue k-major, W from
// global (L1-resident 16KB), y[16] register accumulators. LDS = us (16 KB).
// ---------------------------------------------------------------------------
__global__ __launch_bounds__(256) void gg_kernel(
    const __half* __restrict__ h, const int* __restrict__ ssrc,
    const int* __restrict__ rowptr, const float* __restrict__ ns,
    const float* __restrict__ nd, const float* __restrict__ bprev,
    const float* __restrict__ W, __half* __restrict__ hout,
    int N, int swiz)
{
    __shared__ float us[GGN][64];        // 16 KB
    int blk = blockIdx.x;
    if (swiz) {                          // 1024 blocks: 16 graphs x 64
        int xg = blk & 7;
        int j = blk >> 3;
        int g = xg + ((j >> 6) << 3);
        blk = (g << 6) + (j & 63);
    }
    const int tid = threadIdx.x;
    const int wv = tid >> 6;
    const int lane = tid & 63;
    const int grp = lane >> 3;           // 8 node slots per wave
    const int sub = lane & 7;            // dim octet

    const int nlA = wv * 8 + grp;        // nodes 0..31
    const int nlB = nlA + 32;            // nodes 32..63
    const int wA = blk * GGN + nlA;
    const int wB = blk * GGN + nlB;
    if (wB < N) {
        int begA = rowptr[wA], endA = rowptr[wA + 1];
        int begB = rowptr[wB], endB = rowptr[wB + 1];
        float4 accA0 = {0,0,0,0}, accA1 = {0,0,0,0};
        float4 accB0 = {0,0,0,0}, accB1 = {0,0,0,0};
        gather_node2(h, ssrc, begA, endA, begB, endB, sub,
                     accA0, accA1, accB0, accB1);
        float4 bv0 = *(const float4*)(bprev + sub * 8);
        float4 bv1 = *(const float4*)(bprev + sub * 8 + 4);
        {
            float sw = ns[wA];
            float alpha = nd[wA] * sw;
            float4 u0, u1;
            u0.x = accA0.x * alpha + sw * bv0.x;
            u0.y = accA0.y * alpha + sw * bv0.y;
            u0.z = accA0.z * alpha + sw * bv0.z;
            u0.w = accA0.w * alpha + sw * bv0.w;
            u1.x = accA1.x * alpha + sw * bv1.x;
            u1.y = accA1.y * alpha + sw * bv1.y;
            u1.z = accA1.z * alpha + sw * bv1.z;
            u1.w = accA1.w * alpha + sw * bv1.w;
            *(float4*)&us[nlA][sub * 8    ] = u0;
            *(float4*)&us[nlA][sub * 8 + 4] = u1;
        }
        {
            float sw = ns[wB];
            float alpha = nd[wB] * sw;
            float4 u0, u1;
            u0.x = accB0.x * alpha + sw * bv0.x;
            u0.y = accB0.y * alpha + sw * bv0.y;
            u0.z = accB0.z * alpha + sw * bv0.z;
            u0.w = accB0.w * alpha + sw * bv0.w;
            u1.x = accB1.x * alpha + sw * bv1.x;
            u1.y = accB1.y * alpha + sw * bv1.y;
            u1.z = accB1.z * alpha + sw * bv1.z;
            u1.w = accB1.w * alpha + sw * bv1.w;
            *(float4*)&us[nlB][sub * 8    ] = u0;
            *(float4*)&us[nlB][sub * 8 + 4] = u1;
        }
    }
    __syncthreads();
    // Epilogue GEMM: thread -> col c, nodes nb+4m (m=0..15). us reads are
    // wave-uniform broadcasts; W[k*64+c] stride-1 coalesced, L1-hot.
    const int c = tid & 63;
    const int nb = tid >> 6;
    float y[16];
#pragma unroll
    for (int m = 0; m < 16; ++m) y[m] = 0.f;
#pragma unroll
    for (int k = 0; k < 64; k += 4) {
        float w0 = W[(k    ) * 64 + c];
        float w1 = W[(k + 1) * 64 + c];
        float w2 = W[(k + 2) * 64 + c];
        float w3 = W[(k + 3) * 64 + c];
#pragma unroll
        for (int m = 0; m < 16; ++m) {
            const float4 uv = *(const float4*)&us[nb + 4 * m][k];
            y[m] += uv.x * w0 + uv.y * w1 + uv.z * w2 + uv.w * w3;
        }
    }
#pragma unroll
    for (int m = 0; m < 16; ++m) {
        int wo = blk * GGN + nb + 4 * m;
        if (wo < N)
            hout[(size_t)wo * 64 + c] = __float2half_rn(y[m]);
    }
}

// ---------------------------------------------------------------------------
// Final gather (layer 3): uint4 dual-stream, acc*nd + b3 -> fp32 out.
// 4 waves x 8 groups x 2 nodes = 64 nodes/block.
// ---------------------------------------------------------------------------
__global__ __launch_bounds__(256) void gather_kernel(
    const __half* __restrict__ h, const int* __restrict__ ssrc,
    const int* __restrict__ rowptr, float* __restrict__ out,
    const float* __restrict__ nd, const float* __restrict__ b,
    int N, int swiz)
{
    int blk = blockIdx.x;
    if (swiz) {                        // 1024 blocks: 16 graphs x 64
        int x = blk & 7;
        int j = blk >> 3;
        int g = x + ((j >> 6) << 3);
        blk = (g << 6) + (j & 63);
    }
    const int wv = threadIdx.x >> 6;
    const int lane = threadIdx.x & 63;
    const int grp = lane >> 3;
    const int sub = lane & 7;
    int wA = blk * 64 + wv * 8 + grp;
    int wB = wA + 32;
    if (wB >= N) return;
    int begA = rowptr[wA], endA = rowptr[wA + 1];
    int begB = rowptr[wB], endB = rowptr[wB + 1];
    float4 accA0 = {0,0,0,0}, accA1 = {0,0,0,0};
    float4 accB0 = {0,0,0,0}, accB1 = {0,0,0,0};
    gather_node2(h, ssrc, begA, endA, begB, endB, sub,
                 accA0, accA1, accB0, accB1);
    const float4 bv0 = *(const float4*)(b + sub * 8);
    const float4 bv1 = *(const float4*)(b + sub * 8 + 4);
    {
        float n = nd[wA];
        accA0.x = accA0.x * n + bv0.x; accA0.y = accA0.y * n + bv0.y;
        accA0.z = accA0.z * n + bv0.z; accA0.w = accA0.w * n + bv0.w;
        accA1.x = accA1.x * n + bv1.x; accA1.y = accA1.y * n + bv1.y;
        accA1.z = accA1.z * n + bv1.z; accA1.w = accA1.w * n + bv1.w;
        *(float4*)(out + (size_t)wA * 64 + sub * 8    ) = accA0;
        *(float4*)(out + (size_t)wA * 64 + sub * 8 + 4) = accA1;
    }
    {
        float n = nd[wB];
        accB0.x = accB0.x * n + bv0.x; accB0.y = accB0.y * n + bv0.y;
        accB0.z = accB0.z * n + bv0.z; accB0.w = accB0.w * n + bv0.w;
        accB1.x = accB1.x * n + bv1.x; accB1.y = accB1.y * n + bv1.y;
        accB1.z = accB1.z * n + bv1.z; accB1.w = accB1.w * n + bv1.w;
        *(float4*)(out + (size_t)wB * 64 + sub * 8    ) = accB0;
        *(float4*)(out + (size_t)wB * 64 + sub * 8 + 4) = accB1;
    }
}

// ---------------------------------------------------------------------------
extern "C" void kernel_launch(void* const* d_in, const int* in_sizes, int n_in,
                              void* d_out, int out_size, void* d_ws, size_t ws_size,
                              hipStream_t stream)
{
    const float* x  = (const float*)d_in[0];
    const float* W1 = (const float*)d_in[1];
    const float* b1 = (const float*)d_in[2];
    const float* W2 = (const float*)d_in[3];
    const float* b2 = (const float*)d_in[4];
    const float* W3 = (const float*)d_in[5];
    const float* b3 = (const float*)d_in[6];
    const int*  src = (const int*)d_in[7];
    const int*  dst = (const int*)d_in[8];

    const int E = in_sizes[7];
    const int N = in_sizes[0] / DIM;
    const int epg = E / NG;
    const int npg = N / NG;
    const int chunk = epg / CPG;

    // ws: ns[N] | nd[N] | degd[N] | hF[N*64 h] | h2[N*64 h] | rowptr[N+1]
    //     | ssrc[E] | hsub[HISTB*npg] | dsub[HISTB*npg]   (~30 MB)
    float*  ns     = (float*)d_ws;
    float*  nd     = ns + N;
    int*    degd   = (int*)(nd + N);
    __half* hF     = (__half*)(degd + N);
    __half* h2     = hF + (size_t)N * DIM;
    int*    rowptr = (int*)(h2 + (size_t)N * DIM);
    int*    ssrc   = rowptr + N + 1;
    int*    hsub   = ssrc + E;
    int*    dsub   = hsub + (size_t)HISTB * npg;
    float*  agg    = (float*)d_out;

    const int swiz = (N == 65536 && npg == 4096) ? 1 : 0;

    kA_hist<<<HISTB, 256, 0, stream>>>(src, dst, hsub, dsub, chunk, npg);
    k2a_norms<<<N / 256, 256, 0, stream>>>(hsub, dsub, ns, nd, degd, npg);
    k2b_scan<<<NG, 1024, 0, stream>>>(degd, rowptr, epg, npg, N, E);
    k2c_cursors<<<N / 256, 256, 0, stream>>>(dsub, rowptr, npg);
    kC_gemm_fill<<<HISTB + N / 32, 256, 0, stream>>>(
        src, dst, dsub, ssrc, chunk, npg, x, W1, ns, hF, swiz);

    gg_kernel<<<(N + GGN - 1) / GGN, 256, 0, stream>>>(
        hF, ssrc, rowptr, ns, nd, b1, W2, h2, N, swiz);
    gg_kernel<<<(N + GGN - 1) / GGN, 256, 0, stream>>>(
        h2, ssrc, rowptr, ns, nd, b2, W3, hF, N, swiz);
    gather_kernel<<<(N + 63) / 64, 256, 0, stream>>>(
        hF, ssrc, rowptr, agg, nd, b3, N, swiz);
}

// Round 9
// 218.372 us; speedup vs baseline: 3.1414x; 3.1414x over previous
//
#include <hip/hip_runtime.h>
#include <hip/hip_fp16.h>

#define DIM 64
#define NG  16          // num graphs
#define CPG 16          // edge chunks per graph (hist/fill parallelism)
#define NPG 4096        // nodes per graph
#define LSTR 68
#define HISTB (NG*CPG)  // 256 hist/fill blocks
#define GGN 32          // dst nodes per fused gather+gemm block

// ---------------------------------------------------------------------------
// kA: per-chunk LDS degree histograms. 256 blocks.
// ---------------------------------------------------------------------------
__global__ __launch_bounds__(256) void kA_hist(
    const int* __restrict__ src, const int* __restrict__ dst,
    int* __restrict__ hsub, int* __restrict__ dsub, int chunk, int npg)
{
    __shared__ int hs[NPG], hd[NPG];
    const int blk = blockIdx.x;
    const int g = blk / CPG;
    const int t = threadIdx.x;
    const int ebase = blk * chunk;
    const int nbase = g * npg;
    for (int i = t; i < npg; i += 256) { hs[i] = 0; hd[i] = 0; }
    __syncthreads();
    for (int e = t; e < chunk; e += 256) {
        atomicAdd(&hs[src[ebase + e] - nbase], 1);
        atomicAdd(&hd[dst[ebase + e] - nbase], 1);
    }
    __syncthreads();
    for (int i = t; i < npg; i += 256) {
        hsub[blk * npg + i] = hs[i];
        dsub[blk * npg + i] = hd[i];
    }
}

// ---------------------------------------------------------------------------
// k2a: full-GPU chunk reduction. One thread per node: sum the CPG sub-hists
// -> ns/nd/degd. Fully coalesced, 256 blocks.
// ---------------------------------------------------------------------------
__global__ __launch_bounds__(256) void k2a_norms(
    const int* __restrict__ hsub, const int* __restrict__ dsub,
    float* __restrict__ ns, float* __restrict__ nd, int* __restrict__ degd,
    int npg)
{
    const int node = blockIdx.x * 256 + threadIdx.x;
    const int g = node / npg;
    const int i = node - g * npg;
    int sd = 0, dd = 0;
#pragma unroll
    for (int k = 0; k < CPG; ++k) {
        sd += hsub[(g * CPG + k) * npg + i];
        dd += dsub[(g * CPG + k) * npg + i];
    }
    ns[node] = sd > 0 ? rsqrtf((float)sd) : 0.0f;
    nd[node] = dd > 0 ? rsqrtf((float)dd) : 0.0f;
    degd[node] = dd;
}

// ---------------------------------------------------------------------------
// k2b: per-graph exclusive scan of in-degrees -> rowptr. 16 blocks but reads
// only 256 KB (degd) instead of 16 MB.
// ---------------------------------------------------------------------------
__global__ __launch_bounds__(1024) void k2b_scan(
    const int* __restrict__ degd, int* __restrict__ rowptr,
    int epg, int npg, int N, int E)
{
    __shared__ int wsum[16];
    const int g = blockIdx.x;
    const int t = threadIdx.x;
    const int nbase = g * npg;
    const int ebase = g * epg;
    const int i0 = 4 * t;
    const int4 d = *(const int4*)&degd[nbase + i0];
    int s4 = d.x + d.y + d.z + d.w;
    const int lane = t & 63, wid = t >> 6;
    int v = s4;
#pragma unroll
    for (int off = 1; off < 64; off <<= 1) {
        int u = __shfl_up(v, off, 64);
        if (lane >= off) v += u;
    }
    if (lane == 63) wsum[wid] = v;
    __syncthreads();
    if (t < 16) {
        int w = wsum[t];
#pragma unroll
        for (int off = 1; off < 16; off <<= 1) {
            int u = __shfl_up(w, off, 16);
            if (t >= off) w += u;
        }
        wsum[t] = w;
    }
    __syncthreads();
    int incl = v + (wid > 0 ? wsum[wid - 1] : 0);
    int c = ebase + incl - s4;
    rowptr[nbase + i0    ] = c; c += d.x;
    rowptr[nbase + i0 + 1] = c; c += d.y;
    rowptr[nbase + i0 + 2] = c; c += d.z;
    rowptr[nbase + i0 + 3] = c;
    if (g == 0 && t == 0) rowptr[N] = E;
}

// ---------------------------------------------------------------------------
// k2c: full-GPU cursor rewrite. One thread per node: in-place prefix of the
// CPG sub-counts -> per-chunk ABSOLUTE cursor starts. Coalesced per k.
// ---------------------------------------------------------------------------
__global__ __launch_bounds__(256) void k2c_cursors(
    int* __restrict__ dsub, const int* __restrict__ rowptr, int npg)
{
    const int node = blockIdx.x * 256 + threadIdx.x;
    const int g = node / npg;
    const int i = node - g * npg;
    int cc = rowptr[node];
#pragma unroll
    for (int k = 0; k < CPG; ++k) {
        int* p = &dsub[(g * CPG + k) * npg + i];
        int old = *p; *p = cc; cc += old;
    }
}

// ---------------------------------------------------------------------------
// kC: fused. Blocks [0,HISTB): fill ssrc via LDS cursors (stable counting
// sort). Blocks [HISTB, HISTB+N/32): hF = fp16( (ns ⊙ x) @ W1 ).
// ---------------------------------------------------------------------------
__global__ __launch_bounds__(256) void kC_gemm_fill(
    const int* __restrict__ src, const int* __restrict__ dst,
    const int* __restrict__ dsub, int* __restrict__ ssrc, int chunk, int npg,
    const float* __restrict__ x, const float* __restrict__ W1,
    const float* __restrict__ ns, __half* __restrict__ hF, int swiz)
{
    __shared__ float smem[64 * LSTR + 32 * LSTR];   // 26 KB (fill uses 16 KB)
    const int tid = threadIdx.x;
    if ((int)blockIdx.x < HISTB) {
        int* cur = (int*)smem;
        const int blk = blockIdx.x;
        const int g = blk / CPG;
        const int ebase = blk * chunk;
        const int nbase = g * npg;
        for (int i = tid; i < npg; i += 256) cur[i] = dsub[blk * npg + i];
        __syncthreads();
        for (int e = tid; e < chunk; e += 256) {
            int s = src[ebase + e];
            int d = dst[ebase + e] - nbase;
            int pos = atomicAdd(&cur[d], 1);
            ssrc[pos] = s;
        }
    } else {
        float* Wt = smem;                    // Wt[c][k], 64*LSTR
        float* xs = Wt + 64 * LSTR;          // xs[r][k], 32*LSTR
        int blk = blockIdx.x - HISTB;
        if (swiz) {                          // 2048 blocks: 16 graphs x 128
            int xg = blk & 7;
            int j = blk >> 3;
            int g = xg + ((j >> 7) << 3);
            blk = (g << 7) + (j & 127);
        }
        const int row0 = blk * 32;
        for (int i = tid; i < 64 * 64; i += 256) {
            int k = i >> 6, c = i & 63;
            Wt[c * LSTR + k] = W1[i];
        }
        for (int i = tid; i < 32 * 64; i += 256) {
            int r = i >> 6, c = i & 63;
            int row = row0 + r;
            xs[r * LSTR + c] = x[(size_t)row * 64 + c] * ns[row];
        }
        __syncthreads();
        const int c0 = tid & 31;
        const int r0 = tid >> 5;
        float acc[4][2] = {};
#pragma unroll
        for (int k = 0; k < 64; k += 4) {
            float4 w0 = *(const float4*)&Wt[(c0     ) * LSTR + k];
            float4 w1 = *(const float4*)&Wt[(c0 + 32) * LSTR + k];
#pragma unroll
            for (int rr = 0; rr < 4; ++rr) {
                float4 xv = *(const float4*)&xs[(r0 + 8 * rr) * LSTR + k];
                acc[rr][0] += xv.x * w0.x + xv.y * w0.y + xv.z * w0.z + xv.w * w0.w;
                acc[rr][1] += xv.x * w1.x + xv.y * w1.y + xv.z * w1.z + xv.w * w1.w;
            }
        }
#pragma unroll
        for (int rr = 0; rr < 4; ++rr) {
            int row = row0 + r0 + 8 * rr;
            hF[(size_t)row * 64 + c0     ] = __float2half_rn(acc[rr][0]);
            hF[(size_t)row * 64 + c0 + 32] = __float2half_rn(acc[rr][1]);
        }
    }
}

// ---------------------------------------------------------------------------
// Gather core (R7-verified): 16 lanes per node, uint2 (8B) per edge.
// Dual-node stream for within-iteration MLP + IDX-ONLY cross-iteration carry.
// REGISTER-BUDGET LAW (R4/R8): uint2 x 2 streams (~40 VGPR data) fits;
// uint4 x 2 streams (~128) spills past the 256 cliff -- do not widen.
// ---------------------------------------------------------------------------
__device__ __forceinline__ void acc_h4(float4& acc, uint2 u)
{
    __half2 p = *(__half2*)&u.x;
    __half2 q = *(__half2*)&u.y;
    float2 f0 = __half22float2(p);
    float2 f1 = __half22float2(q);
    acc.x += f0.x; acc.y += f0.y; acc.z += f1.x; acc.w += f1.y;
}

__device__ __forceinline__ void acc_h4s(float4& acc, uint2 u, float s)
{
    __half2 p = *(__half2*)&u.x;
    __half2 q = *(__half2*)&u.y;
    float2 f0 = __half22float2(p);
    float2 f1 = __half22float2(q);
    acc.x += s * f0.x; acc.y += s * f0.y; acc.z += s * f1.x; acc.w += s * f1.y;
}

// single-stream remainder: full 8-batches then predicated tail (<8)
__device__ __forceinline__ void gather_rest(
    const __half* __restrict__ h, const int* __restrict__ ssrc,
    int j, int end, int sub, float4& acc)
{
    const size_t off = (size_t)sub * 4;
    const int last = end - 8;
    while (j <= last) {
        int s0 = ssrc[j+0], s1 = ssrc[j+1], s2 = ssrc[j+2], s3 = ssrc[j+3];
        int s4 = ssrc[j+4], s5 = ssrc[j+5], s6 = ssrc[j+6], s7 = ssrc[j+7];
        uint2 u0 = *(const uint2*)(h + (size_t)s0 * 64 + off);
        uint2 u1 = *(const uint2*)(h + (size_t)s1 * 64 + off);
        uint2 u2 = *(const uint2*)(h + (size_t)s2 * 64 + off);
        uint2 u3 = *(const uint2*)(h + (size_t)s3 * 64 + off);
        uint2 u4 = *(const uint2*)(h + (size_t)s4 * 64 + off);
        uint2 u5 = *(const uint2*)(h + (size_t)s5 * 64 + off);
        uint2 u6 = *(const uint2*)(h + (size_t)s6 * 64 + off);
        uint2 u7 = *(const uint2*)(h + (size_t)s7 * 64 + off);
        acc_h4(acc, u0); acc_h4(acc, u1); acc_h4(acc, u2); acc_h4(acc, u3);
        acc_h4(acc, u4); acc_h4(acc, u5); acc_h4(acc, u6); acc_h4(acc, u7);
        j += 8;
    }
    int rem = end - j;      // 0..7
    if (rem > 0) {
#pragma unroll
        for (int q = 0; q < 4; ++q) {
            int jj = j + (q < rem ? q : rem - 1);    // clamped: always valid
            int s = ssrc[jj];
            uint2 u = *(const uint2*)(h + (size_t)s * 64 + off);
            acc_h4s(acc, u, (q < rem) ? 1.0f : 0.0f);
        }
        if (rem > 4) {
#pragma unroll
            for (int q = 4; q < 8; ++q) {
                int jj = j + (q < rem ? q : rem - 1);
                int s = ssrc[jj];
                uint2 u = *(const uint2*)(h + (size_t)s * 64 + off);
                acc_h4s(acc, u, (q < rem) ? 1.0f : 0.0f);
            }
        }
    }
}

__device__ __forceinline__ void gather_node2(
    const __half* __restrict__ h, const int* __restrict__ ssrc,
    int begA, int endA, int begB, int endB, int sub,
    float4& accA, float4& accB)
{
    const size_t off = (size_t)sub * 4;
    int jA = begA, jB = begB;
    const int lastA = endA - 8, lastB = endB - 8;
    if (jA <= lastA && jB <= lastB) {
        // prologue: idx batch 0
        int a0 = ssrc[jA+0], a1 = ssrc[jA+1], a2 = ssrc[jA+2], a3 = ssrc[jA+3];
        int a4 = ssrc[jA+4], a5 = ssrc[jA+5], a6 = ssrc[jA+6], a7 = ssrc[jA+7];
        int b0 = ssrc[jB+0], b1 = ssrc[jB+1], b2 = ssrc[jB+2], b3 = ssrc[jB+3];
        int b4 = ssrc[jB+4], b5 = ssrc[jB+5], b6 = ssrc[jB+6], b7 = ssrc[jB+7];
        for (;;) {
            // issue data batch k (idx resident)
            uint2 uA0 = *(const uint2*)(h + (size_t)a0 * 64 + off);
            uint2 uA1 = *(const uint2*)(h + (size_t)a1 * 64 + off);
            uint2 uA2 = *(const uint2*)(h + (size_t)a2 * 64 + off);
            uint2 uA3 = *(const uint2*)(h + (size_t)a3 * 64 + off);
            uint2 uA4 = *(const uint2*)(h + (size_t)a4 * 64 + off);
            uint2 uA5 = *(const uint2*)(h + (size_t)a5 * 64 + off);
            uint2 uA6 = *(const uint2*)(h + (size_t)a6 * 64 + off);
            uint2 uA7 = *(const uint2*)(h + (size_t)a7 * 64 + off);
            uint2 uB0 = *(const uint2*)(h + (size_t)b0 * 64 + off);
            uint2 uB1 = *(const uint2*)(h + (size_t)b1 * 64 + off);
            uint2 uB2 = *(const uint2*)(h + (size_t)b2 * 64 + off);
            uint2 uB3 = *(const uint2*)(h + (size_t)b3 * 64 + off);
            uint2 uB4 = *(const uint2*)(h + (size_t)b4 * 64 + off);
            uint2 uB5 = *(const uint2*)(h + (size_t)b5 * 64 + off);
            uint2 uB6 = *(const uint2*)(h + (size_t)b6 * 64 + off);
            uint2 uB7 = *(const uint2*)(h + (size_t)b7 * 64 + off);
            jA += 8; jB += 8;
            bool more = (jA <= lastA) && (jB <= lastB);
            // issue idx batch k+1 (branchless; clamp to known-valid base)
            int pA = more ? jA : begA;
            int pB = more ? jB : begB;
            int na0 = ssrc[pA+0], na1 = ssrc[pA+1], na2 = ssrc[pA+2], na3 = ssrc[pA+3];
            int na4 = ssrc[pA+4], na5 = ssrc[pA+5], na6 = ssrc[pA+6], na7 = ssrc[pA+7];
            int nb0 = ssrc[pB+0], nb1 = ssrc[pB+1], nb2 = ssrc[pB+2], nb3 = ssrc[pB+3];
            int nb4 = ssrc[pB+4], nb5 = ssrc[pB+5], nb6 = ssrc[pB+6], nb7 = ssrc[pB+7];
            // consume data batch k (waits older loads only; idx stays in flight)
            acc_h4(accA, uA0); acc_h4(accA, uA1); acc_h4(accA, uA2); acc_h4(accA, uA3);
            acc_h4(accA, uA4); acc_h4(accA, uA5); acc_h4(accA, uA6); acc_h4(accA, uA7);
            acc_h4(accB, uB0); acc_h4(accB, uB1); acc_h4(accB, uB2); acc_h4(accB, uB3);
            acc_h4(accB, uB4); acc_h4(accB, uB5); acc_h4(accB, uB6); acc_h4(accB, uB7);
            if (!more) break;
            a0 = na0; a1 = na1; a2 = na2; a3 = na3;
            a4 = na4; a5 = na5; a6 = na6; a7 = na7;
            b0 = nb0; b1 = nb1; b2 = nb2; b3 = nb3;
            b4 = nb4; b5 = nb5; b6 = nb6; b7 = nb7;
        }
    }
    gather_rest(h, ssrc, jA, endA, sub, accA);
    gather_rest(h, ssrc, jB, endB, sub, accB);
}

// ---------------------------------------------------------------------------
// Fused gather + next-layer GEMM (h pre-scaled by ns). Per dst node w:
//   acc = sum h[s];  u = acc*(nd*ns) + ns*bprev;  y = u @ W;  hout = fp16(y)
// 4 waves x 4 groups x 2 nodes = 32 nodes. Epilogue k-major, W from global
// (L1-resident 16KB), y[8] register accumulators. LDS = us only (8 KB).
// ---------------------------------------------------------------------------
__global__ __launch_bounds__(256) void gg_kernel(
    const __half* __restrict__ h, const int* __restrict__ ssrc,
    const int* __restrict__ rowptr, const float* __restrict__ ns,
    const float* __restrict__ nd, const float* __restrict__ bprev,
    const float* __restrict__ W, __half* __restrict__ hout,
    int N, int swiz)
{
    __shared__ float us[GGN][64];        // scaled agg rows, 8 KB
    int blk = blockIdx.x;
    if (swiz) {                          // 2048 blocks: 16 graphs x 128
        int xg = blk & 7;
        int j = blk >> 3;
        int g = xg + ((j >> 7) << 3);
        blk = (g << 7) + (j & 127);
    }
    const int tid = threadIdx.x;
    const int wv = tid >> 6;
    const int lane = tid & 63;
    const int grp = lane >> 4;           // node slot within wave
    const int sub = lane & 15;           // dim quad

    const int nlA = wv * 4 + grp;        // nodes 0..15
    const int nlB = nlA + 16;            // nodes 16..31
    const int wA = blk * GGN + nlA;
    const int wB = blk * GGN + nlB;
    {
        int begA = rowptr[wA], endA = rowptr[wA + 1];
        int begB = rowptr[wB], endB = rowptr[wB + 1];
        float4 accA = {0.f,0.f,0.f,0.f}, accB = {0.f,0.f,0.f,0.f};
        gather_node2(h, ssrc, begA, endA, begB, endB, sub, accA, accB);
        float4 bv = *(const float4*)(bprev + sub * 4);
        {
            float sw = ns[wA];
            float alpha = nd[wA] * sw;
            float4 uo;
            uo.x = accA.x * alpha + sw * bv.x;
            uo.y = accA.y * alpha + sw * bv.y;
            uo.z = accA.z * alpha + sw * bv.z;
            uo.w = accA.w * alpha + sw * bv.w;
            *(float4*)&us[nlA][sub * 4] = uo;
        }
        {
            float sw = ns[wB];
            float alpha = nd[wB] * sw;
            float4 uo;
            uo.x = accB.x * alpha + sw * bv.x;
            uo.y = accB.y * alpha + sw * bv.y;
            uo.z = accB.z * alpha + sw * bv.z;
            uo.w = accB.w * alpha + sw * bv.w;
            *(float4*)&us[nlB][sub * 4] = uo;
        }
    }
    __syncthreads();
    // Epilogue GEMM: thread -> col c, nodes nb+4m. us reads are wave-uniform
    // broadcasts; W[k*64+c] is stride-1 coalesced, L1-hot after first block.
    const int c = tid & 63;
    const int nb = tid >> 6;
    float y[8] = {0.f,0.f,0.f,0.f,0.f,0.f,0.f,0.f};
#pragma unroll
    for (int k = 0; k < 64; k += 4) {
        float w0 = W[(k    ) * 64 + c];
        float w1 = W[(k + 1) * 64 + c];
        float w2 = W[(k + 2) * 64 + c];
        float w3 = W[(k + 3) * 64 + c];
#pragma unroll
        for (int m = 0; m < 8; ++m) {
            const float4 uv = *(const float4*)&us[nb + 4 * m][k];
            y[m] += uv.x * w0 + uv.y * w1 + uv.z * w2 + uv.w * w3;
        }
    }
#pragma unroll
    for (int m = 0; m < 8; ++m) {
        int wo = blk * GGN + nb + 4 * m;
        hout[(size_t)wo * 64 + c] = __float2half_rn(y[m]);
    }
}

// ---------------------------------------------------------------------------
// Final gather (layer 3): uint2 dual-stream, acc*nd + b3 -> fp32 out.
// 4 waves x 4 groups x 2 nodes = 32 nodes/block.
// ---------------------------------------------------------------------------
__global__ __launch_bounds__(256) void gather_kernel(
    const __half* __restrict__ h, const int* __restrict__ ssrc,
    const int* __restrict__ rowptr, float* __restrict__ out,
    const float* __restrict__ nd, const float* __restrict__ b,
    int N, int swiz)
{
    int blk = blockIdx.x;
    if (swiz) {                        // 2048 blocks: 16 graphs x 128
        int x = blk & 7;
        int j = blk >> 3;
        int g = x + ((j >> 7) << 3);
        blk = (g << 7) + (j & 127);
    }
    const int wv = threadIdx.x >> 6;
    const int lane = threadIdx.x & 63;
    const int grp = lane >> 4;
    const int sub = lane & 15;
    int wA = blk * 32 + wv * 4 + grp;
    int wB = wA + 16;
    int begA = rowptr[wA], endA = rowptr[wA + 1];
    int begB = rowptr[wB], endB = rowptr[wB + 1];
    float4 accA = {0.f,0.f,0.f,0.f}, accB = {0.f,0.f,0.f,0.f};
    gather_node2(h, ssrc, begA, endA, begB, endB, sub, accA, accB);
    const float4 bv = *(const float4*)(b + sub * 4);
    {
        float n = nd[wA];
        accA.x = accA.x * n + bv.x;
        accA.y = accA.y * n + bv.y;
        accA.z = accA.z * n + bv.z;
        accA.w = accA.w * n + bv.w;
        *(float4*)(out + (size_t)wA * 64 + sub * 4) = accA;
    }
    {
        float n = nd[wB];
        accB.x = accB.x * n + bv.x;
        accB.y = accB.y * n + bv.y;
        accB.z = accB.z * n + bv.z;
        accB.w = accB.w * n + bv.w;
        *(float4*)(out + (size_t)wB * 64 + sub * 4) = accB;
    }
}

// ---------------------------------------------------------------------------
extern "C" void kernel_launch(void* const* d_in, const int* in_sizes, int n_in,
                              void* d_out, int out_size, void* d_ws, size_t ws_size,
                              hipStream_t stream)
{
    const float* x  = (const float*)d_in[0];
    const float* W1 = (const float*)d_in[1];
    const float* b1 = (const float*)d_in[2];
    const float* W2 = (const float*)d_in[3];
    const float* b2 = (const float*)d_in[4];
    const float* W3 = (const float*)d_in[5];
    const float* b3 = (const float*)d_in[6];
    const int*  src = (const int*)d_in[7];
    const int*  dst = (const int*)d_in[8];

    const int E = in_sizes[7];
    const int N = in_sizes[0] / DIM;
    const int epg = E / NG;
    const int npg = N / NG;
    const int chunk = epg / CPG;

    // ws: ns[N] | nd[N] | degd[N] | hF[N*64 h] | h2[N*64 h] | rowptr[N+1]
    //     | ssrc[E] | hsub[HISTB*npg] | dsub[HISTB*npg]   (~30 MB)
    float*  ns     = (float*)d_ws;
    float*  nd     = ns + N;
    int*    degd   = (int*)(nd + N);
    __half* hF     = (__half*)(degd + N);
    __half* h2     = hF + (size_t)N * DIM;
    int*    rowptr = (int*)(h2 + (size_t)N * DIM);
    int*    ssrc   = rowptr + N + 1;
    int*    hsub   = ssrc + E;
    int*    dsub   = hsub + (size_t)HISTB * npg;
    float*  agg    = (float*)d_out;

    const int swiz = (N == 65536 && npg == 4096) ? 1 : 0;

    kA_hist<<<HISTB, 256, 0, stream>>>(src, dst, hsub, dsub, chunk, npg);
    k2a_norms<<<N / 256, 256, 0, stream>>>(hsub, dsub, ns, nd, degd, npg);
    k2b_scan<<<NG, 1024, 0, stream>>>(degd, rowptr, epg, npg, N, E);
    k2c_cursors<<<N / 256, 256, 0, stream>>>(dsub, rowptr, npg);
    kC_gemm_fill<<<HISTB + N / 32, 256, 0, stream>>>(
        src, dst, dsub, ssrc, chunk, npg, x, W1, ns, hF, swiz);

    gg_kernel<<<N / GGN, 256, 0, stream>>>(
        hF, ssrc, rowptr, ns, nd, b1, W2, h2, N, swiz);
    gg_kernel<<<N / GGN, 256, 0, stream>>>(
        h2, ssrc, rowptr, ns, nd, b2, W3, hF, N, swiz);
    gather_kernel<<<N / 32, 256, 0, stream>>>(
        hF, ssrc, rowptr, agg, nd, b3, N, swiz);
}

// Round 10
// 192.868 us; speedup vs baseline: 3.5568x; 1.1322x over previous
//
#include <hip/hip_runtime.h>
#include <hip/hip_fp16.h>

#define DIM 64
#define NG  16          // num graphs
#define CPG 16          // edge chunks per graph (hist/fill parallelism)
#define NPG 4096        // nodes per graph
#define LSTR 68
#define HISTB (NG*CPG)  // 256 hist/fill blocks
#define GGN 32          // dst nodes per fused gather+gemm block

// ---------------------------------------------------------------------------
// kA: per-chunk LDS degree histograms. 256 blocks.
// ---------------------------------------------------------------------------
__global__ __launch_bounds__(256) void kA_hist(
    const int* __restrict__ src, const int* __restrict__ dst,
    int* __restrict__ hsub, int* __restrict__ dsub, int chunk, int npg)
{
    __shared__ int hs[NPG], hd[NPG];
    const int blk = blockIdx.x;
    const int g = blk / CPG;
    const int t = threadIdx.x;
    const int ebase = blk * chunk;
    const int nbase = g * npg;
    for (int i = t; i < npg; i += 256) { hs[i] = 0; hd[i] = 0; }
    __syncthreads();
    for (int e = t; e < chunk; e += 256) {
        atomicAdd(&hs[src[ebase + e] - nbase], 1);
        atomicAdd(&hd[dst[ebase + e] - nbase], 1);
    }
    __syncthreads();
    for (int i = t; i < npg; i += 256) {
        hsub[blk * npg + i] = hs[i];
        dsub[blk * npg + i] = hd[i];
    }
}

// ---------------------------------------------------------------------------
// K2 (monolithic -- R9 showed the 3-way split costs ~5us net): one block per
// graph. Sub-hist reduce -> norms; shuffle scan -> rowptr; in-place prefix
// over chunks -> per-chunk absolute cursor starts.
// ---------------------------------------------------------------------------
__global__ __launch_bounds__(1024) void k2_scan(
    const int* __restrict__ hsub, int* __restrict__ dsub,
    float* __restrict__ ns, float* __restrict__ nd,
    int* __restrict__ rowptr, int epg, int npg, int N, int E)
{
    __shared__ int ddeg[NPG];       // 16 KB: degrees, then starts
    __shared__ int wsum[16];
    const int g = blockIdx.x;
    const int t = threadIdx.x;
    const int nbase = g * npg;
    const int ebase = g * epg;
    for (int i = t; i < npg; i += 1024) {
        int sd = 0, dd = 0;
#pragma unroll
        for (int k = 0; k < CPG; ++k) {
            sd += hsub[(g * CPG + k) * npg + i];
            dd += dsub[(g * CPG + k) * npg + i];
        }
        ns[nbase + i] = sd > 0 ? rsqrtf((float)sd) : 0.0f;
        nd[nbase + i] = dd > 0 ? rsqrtf((float)dd) : 0.0f;
        ddeg[i] = dd;
    }
    __syncthreads();
    const int i0 = 4 * t;
    int d0 = ddeg[i0], d1 = ddeg[i0 + 1], d2 = ddeg[i0 + 2], d3 = ddeg[i0 + 3];
    int s4 = d0 + d1 + d2 + d3;
    const int lane = t & 63, wid = t >> 6;
    int v = s4;
#pragma unroll
    for (int off = 1; off < 64; off <<= 1) {
        int u = __shfl_up(v, off, 64);
        if (lane >= off) v += u;
    }
    if (lane == 63) wsum[wid] = v;
    __syncthreads();
    if (t < 16) {
        int w = wsum[t];
#pragma unroll
        for (int off = 1; off < 16; off <<= 1) {
            int u = __shfl_up(w, off, 16);
            if (t >= off) w += u;
        }
        wsum[t] = w;
    }
    __syncthreads();
    int incl = v + (wid > 0 ? wsum[wid - 1] : 0);
    int c = ebase + incl - s4;
    rowptr[nbase + i0    ] = c; ddeg[i0    ] = c; c += d0;
    rowptr[nbase + i0 + 1] = c; ddeg[i0 + 1] = c; c += d1;
    rowptr[nbase + i0 + 2] = c; ddeg[i0 + 2] = c; c += d2;
    rowptr[nbase + i0 + 3] = c; ddeg[i0 + 3] = c;
    if (g == 0 && t == 0) rowptr[N] = E;
    __syncthreads();
    for (int i = t; i < npg; i += 1024) {
        int cc = ddeg[i];
#pragma unroll
        for (int k = 0; k < CPG; ++k) {
            int* p = &dsub[(g * CPG + k) * npg + i];
            int old = *p; *p = cc; cc += old;
        }
    }
}

// ---------------------------------------------------------------------------
// kC: fused. Blocks [0,HISTB): fill ssrc via LDS cursors (stable counting
// sort). Blocks [HISTB, HISTB+N/32): hF = fp16( (ns ⊙ x) @ W1 ).
// ---------------------------------------------------------------------------
__global__ __launch_bounds__(256) void kC_gemm_fill(
    const int* __restrict__ src, const int* __restrict__ dst,
    const int* __restrict__ dsub, int* __restrict__ ssrc, int chunk, int npg,
    const float* __restrict__ x, const float* __restrict__ W1,
    const float* __restrict__ ns, __half* __restrict__ hF, int swiz)
{
    __shared__ float smem[64 * LSTR + 32 * LSTR];   // 26 KB (fill uses 16 KB)
    const int tid = threadIdx.x;
    if ((int)blockIdx.x < HISTB) {
        int* cur = (int*)smem;
        const int blk = blockIdx.x;
        const int g = blk / CPG;
        const int ebase = blk * chunk;
        const int nbase = g * npg;
        for (int i = tid; i < npg; i += 256) cur[i] = dsub[blk * npg + i];
        __syncthreads();
        for (int e = tid; e < chunk; e += 256) {
            int s = src[ebase + e];
            int d = dst[ebase + e] - nbase;
            int pos = atomicAdd(&cur[d], 1);
            ssrc[pos] = s;
        }
    } else {
        float* Wt = smem;                    // Wt[c][k], 64*LSTR
        float* xs = Wt + 64 * LSTR;          // xs[r][k], 32*LSTR
        int blk = blockIdx.x - HISTB;
        if (swiz) {                          // 2048 blocks: 16 graphs x 128
            int xg = blk & 7;
            int j = blk >> 3;
            int g = xg + ((j >> 7) << 3);
            blk = (g << 7) + (j & 127);
        }
        const int row0 = blk * 32;
        for (int i = tid; i < 64 * 64; i += 256) {
            int k = i >> 6, c = i & 63;
            Wt[c * LSTR + k] = W1[i];
        }
        for (int i = tid; i < 32 * 64; i += 256) {
            int r = i >> 6, c = i & 63;
            int row = row0 + r;
            xs[r * LSTR + c] = x[(size_t)row * 64 + c] * ns[row];
        }
        __syncthreads();
        const int c0 = tid & 31;
        const int r0 = tid >> 5;
        float acc[4][2] = {};
#pragma unroll
        for (int k = 0; k < 64; k += 4) {
            float4 w0 = *(const float4*)&Wt[(c0     ) * LSTR + k];
            float4 w1 = *(const float4*)&Wt[(c0 + 32) * LSTR + k];
#pragma unroll
            for (int rr = 0; rr < 4; ++rr) {
                float4 xv = *(const float4*)&xs[(r0 + 8 * rr) * LSTR + k];
                acc[rr][0] += xv.x * w0.x + xv.y * w0.y + xv.z * w0.z + xv.w * w0.w;
                acc[rr][1] += xv.x * w1.x + xv.y * w1.y + xv.z * w1.z + xv.w * w1.w;
            }
        }
#pragma unroll
        for (int rr = 0; rr < 4; ++rr) {
            int row = row0 + r0 + 8 * rr;
            hF[(size_t)row * 64 + c0     ] = __float2half_rn(acc[rr][0]);
            hF[(size_t)row * 64 + c0 + 32] = __float2half_rn(acc[rr][1]);
        }
    }
}

// ---------------------------------------------------------------------------
// Gather core: 8-lane groups x uint4 x SINGLE stream + idx-only carry.
// Lane sub owns dims [sub*8, sub*8+8) = one uint4 (16B). Per wave-iter:
// 8 groups x 8 edges = 64 edges with 8 data + 8 idx VMEM (half of R7's 32),
// each data instr = 1024B. In-flight data = 8 x uint4 = 32 VGPR -- SAME
// budget as R7's proven 16 x uint2. (Register law: dual-stream uint4 = 128
// VGPR spilled in R4/R8; this is the single-stream point the law permits.)
// ---------------------------------------------------------------------------
__device__ __forceinline__ void acc_u4(float4& A, float4& B, uint4 u)
{
    __half2 h0 = *(__half2*)&u.x;
    __half2 h1 = *(__half2*)&u.y;
    __half2 h2 = *(__half2*)&u.z;
    __half2 h3 = *(__half2*)&u.w;
    float2 f0 = __half22float2(h0), f1 = __half22float2(h1);
    float2 f2 = __half22float2(h2), f3 = __half22float2(h3);
    A.x += f0.x; A.y += f0.y; A.z += f1.x; A.w += f1.y;
    B.x += f2.x; B.y += f2.y; B.z += f3.x; B.w += f3.y;
}

__device__ __forceinline__ void acc_u4s(float4& A, float4& B, uint4 u, float s)
{
    __half2 h0 = *(__half2*)&u.x;
    __half2 h1 = *(__half2*)&u.y;
    __half2 h2 = *(__half2*)&u.z;
    __half2 h3 = *(__half2*)&u.w;
    float2 f0 = __half22float2(h0), f1 = __half22float2(h1);
    float2 f2 = __half22float2(h2), f3 = __half22float2(h3);
    A.x += s * f0.x; A.y += s * f0.y; A.z += s * f1.x; A.w += s * f1.y;
    B.x += s * f2.x; B.y += s * f2.y; B.z += s * f3.x; B.w += s * f3.y;
}

__device__ __forceinline__ void gather_node(
    const __half* __restrict__ h, const int* __restrict__ ssrc,
    int beg, int end, int sub, float4& A, float4& B)
{
    const size_t off = (size_t)sub * 8;
    int j = beg;
    const int last = end - 8;
    if (j <= last) {
        // prologue: idx batch 0
        int s0 = ssrc[j+0], s1 = ssrc[j+1], s2 = ssrc[j+2], s3 = ssrc[j+3];
        int s4 = ssrc[j+4], s5 = ssrc[j+5], s6 = ssrc[j+6], s7 = ssrc[j+7];
        for (;;) {
            // issue data batch k (idx resident)
            uint4 u0 = *(const uint4*)(h + (size_t)s0 * 64 + off);
            uint4 u1 = *(const uint4*)(h + (size_t)s1 * 64 + off);
            uint4 u2 = *(const uint4*)(h + (size_t)s2 * 64 + off);
            uint4 u3 = *(const uint4*)(h + (size_t)s3 * 64 + off);
            uint4 u4 = *(const uint4*)(h + (size_t)s4 * 64 + off);
            uint4 u5 = *(const uint4*)(h + (size_t)s5 * 64 + off);
            uint4 u6 = *(const uint4*)(h + (size_t)s6 * 64 + off);
            uint4 u7 = *(const uint4*)(h + (size_t)s7 * 64 + off);
            j += 8;
            bool more = (j <= last);
            // issue idx batch k+1 (branchless; clamp to known-valid base)
            int p = more ? j : beg;
            int n0 = ssrc[p+0], n1 = ssrc[p+1], n2 = ssrc[p+2], n3 = ssrc[p+3];
            int n4 = ssrc[p+4], n5 = ssrc[p+5], n6 = ssrc[p+6], n7 = ssrc[p+7];
            // consume data batch k (waits older loads only; idx stays in flight)
            acc_u4(A, B, u0); acc_u4(A, B, u1); acc_u4(A, B, u2); acc_u4(A, B, u3);
            acc_u4(A, B, u4); acc_u4(A, B, u5); acc_u4(A, B, u6); acc_u4(A, B, u7);
            if (!more) break;
            s0 = n0; s1 = n1; s2 = n2; s3 = n3;
            s4 = n4; s5 = n5; s6 = n6; s7 = n7;
        }
    }
    int rem = end - j;      // 0..7
    if (rem > 0) {
#pragma unroll
        for (int q = 0; q < 4; ++q) {
            int jj = j + (q < rem ? q : rem - 1);    // clamped: always valid
            int s = ssrc[jj];
            uint4 u = *(const uint4*)(h + (size_t)s * 64 + off);
            acc_u4s(A, B, u, (q < rem) ? 1.0f : 0.0f);
        }
        if (rem > 4) {
#pragma unroll
            for (int q = 4; q < 8; ++q) {
                int jj = j + (q < rem ? q : rem - 1);
                int s = ssrc[jj];
                uint4 u = *(const uint4*)(h + (size_t)s * 64 + off);
                acc_u4s(A, B, u, (q < rem) ? 1.0f : 0.0f);
            }
        }
    }
}

// ---------------------------------------------------------------------------
// Fused gather + next-layer GEMM (h pre-scaled by ns). Per dst node w:
//   acc = sum h[s];  u = acc*(nd*ns) + ns*bprev;  y = u @ W;  hout = fp16(y)
// 4 waves x 8 groups = 32 nodes, one pass. Epilogue k-major, W from global
// (L1-resident 16KB), y[8] register accumulators. LDS = us only (8 KB).
// ---------------------------------------------------------------------------
__global__ __launch_bounds__(256) void gg_kernel(
    const __half* __restrict__ h, const int* __restrict__ ssrc,
    const int* __restrict__ rowptr, const float* __restrict__ ns,
    const float* __restrict__ nd, const float* __restrict__ bprev,
    const float* __restrict__ W, __half* __restrict__ hout,
    int N, int swiz)
{
    __shared__ float us[GGN][64];        // scaled agg rows, 8 KB
    int blk = blockIdx.x;
    if (swiz) {                          // 2048 blocks: 16 graphs x 128
        int xg = blk & 7;
        int j = blk >> 3;
        int g = xg + ((j >> 7) << 3);
        blk = (g << 7) + (j & 127);
    }
    const int tid = threadIdx.x;
    const int wv = tid >> 6;
    const int lane = tid & 63;
    const int grp = lane >> 3;           // 8 node slots per wave
    const int sub = lane & 7;            // dim octet

    const int nl = wv * 8 + grp;         // nodes 0..31
    const int w = blk * GGN + nl;
    {
        int beg = rowptr[w], end = rowptr[w + 1];
        float4 A = {0.f,0.f,0.f,0.f}, B = {0.f,0.f,0.f,0.f};
        gather_node(h, ssrc, beg, end, sub, A, B);
        float sw = ns[w];
        float alpha = nd[w] * sw;
        float4 bv0 = *(const float4*)(bprev + sub * 8);
        float4 bv1 = *(const float4*)(bprev + sub * 8 + 4);
        float4 u0, u1;
        u0.x = A.x * alpha + sw * bv0.x;
        u0.y = A.y * alpha + sw * bv0.y;
        u0.z = A.z * alpha + sw * bv0.z;
        u0.w = A.w * alpha + sw * bv0.w;
        u1.x = B.x * alpha + sw * bv1.x;
        u1.y = B.y * alpha + sw * bv1.y;
        u1.z = B.z * alpha + sw * bv1.z;
        u1.w = B.w * alpha + sw * bv1.w;
        *(float4*)&us[nl][sub * 8    ] = u0;
        *(float4*)&us[nl][sub * 8 + 4] = u1;
    }
    __syncthreads();
    // Epilogue GEMM: thread -> col c, nodes nb+4m. us reads are wave-uniform
    // broadcasts; W[k*64+c] is stride-1 coalesced, L1-hot after first block.
    const int c = tid & 63;
    const int nb = tid >> 6;
    float y[8] = {0.f,0.f,0.f,0.f,0.f,0.f,0.f,0.f};
#pragma unroll
    for (int k = 0; k < 64; k += 4) {
        float w0 = W[(k    ) * 64 + c];
        float w1 = W[(k + 1) * 64 + c];
        float w2 = W[(k + 2) * 64 + c];
        float w3 = W[(k + 3) * 64 + c];
#pragma unroll
        for (int m = 0; m < 8; ++m) {
            const float4 uv = *(const float4*)&us[nb + 4 * m][k];
            y[m] += uv.x * w0 + uv.y * w1 + uv.z * w2 + uv.w * w3;
        }
    }
#pragma unroll
    for (int m = 0; m < 8; ++m) {
        int wo = blk * GGN + nb + 4 * m;
        hout[(size_t)wo * 64 + c] = __float2half_rn(y[m]);
    }
}

// ---------------------------------------------------------------------------
// Final gather (layer 3): 8-lane uint4 single-stream, acc*nd + b3 -> fp32.
// 4 waves x 8 groups = 32 nodes/block.
// ---------------------------------------------------------------------------
__global__ __launch_bounds__(256) void gather_kernel(
    const __half* __restrict__ h, const int* __restrict__ ssrc,
    const int* __restrict__ rowptr, float* __restrict__ out,
    const float* __restrict__ nd, const float* __restrict__ b,
    int N, int swiz)
{
    int blk = blockIdx.x;
    if (swiz) {                        // 2048 blocks: 16 graphs x 128
        int x = blk & 7;
        int j = blk >> 3;
        int g = x + ((j >> 7) << 3);
        blk = (g << 7) + (j & 127);
    }
    const int wv = threadIdx.x >> 6;
    const int lane = threadIdx.x & 63;
    const int grp = lane >> 3;
    const int sub = lane & 7;
    int w = blk * 32 + wv * 8 + grp;
    if (w >= N) return;
    int beg = rowptr[w], end = rowptr[w + 1];
    float4 A = {0.f,0.f,0.f,0.f}, B = {0.f,0.f,0.f,0.f};
    gather_node(h, ssrc, beg, end, sub, A, B);
    float n = nd[w];
    const float4 bv0 = *(const float4*)(b + sub * 8);
    const float4 bv1 = *(const float4*)(b + sub * 8 + 4);
    A.x = A.x * n + bv0.x; A.y = A.y * n + bv0.y;
    A.z = A.z * n + bv0.z; A.w = A.w * n + bv0.w;
    B.x = B.x * n + bv1.x; B.y = B.y * n + bv1.y;
    B.z = B.z * n + bv1.z; B.w = B.w * n + bv1.w;
    *(float4*)(out + (size_t)w * 64 + sub * 8    ) = A;
    *(float4*)(out + (size_t)w * 64 + sub * 8 + 4) = B;
}

// ---------------------------------------------------------------------------
extern "C" void kernel_launch(void* const* d_in, const int* in_sizes, int n_in,
                              void* d_out, int out_size, void* d_ws, size_t ws_size,
                              hipStream_t stream)
{
    const float* x  = (const float*)d_in[0];
    const float* W1 = (const float*)d_in[1];
    const float* b1 = (const float*)d_in[2];
    const float* W2 = (const float*)d_in[3];
    const float* b2 = (const float*)d_in[4];
    const float* W3 = (const float*)d_in[5];
    const float* b3 = (const float*)d_in[6];
    const int*  src = (const int*)d_in[7];
    const int*  dst = (const int*)d_in[8];

    const int E = in_sizes[7];
    const int N = in_sizes[0] / DIM;
    const int epg = E / NG;
    const int npg = N / NG;
    const int chunk = epg / CPG;

    // ws: ns[N] | nd[N] | hF[N*64 h] | h2[N*64 h] | rowptr[N+1] | ssrc[E]
    //     | hsub[HISTB*npg] | dsub[HISTB*npg]   (~30 MB)
    float*  ns     = (float*)d_ws;
    float*  nd     = ns + N;
    __half* hF     = (__half*)(nd + N);
    __half* h2     = hF + (size_t)N * DIM;
    int*    rowptr = (int*)(h2 + (size_t)N * DIM);
    int*    ssrc   = rowptr + N + 1;
    int*    hsub   = ssrc + E;
    int*    dsub   = hsub + (size_t)HISTB * npg;
    float*  agg    = (float*)d_out;

    const int swiz = (N == 65536 && npg == 4096) ? 1 : 0;

    kA_hist<<<HISTB, 256, 0, stream>>>(src, dst, hsub, dsub, chunk, npg);
    k2_scan<<<NG, 1024, 0, stream>>>(
        hsub, dsub, ns, nd, rowptr, epg, npg, N, E);
    kC_gemm_fill<<<HISTB + N / 32, 256, 0, stream>>>(
        src, dst, dsub, ssrc, chunk, npg, x, W1, ns, hF, swiz);

    gg_kernel<<<N / GGN, 256, 0, stream>>>(
        hF, ssrc, rowptr, ns, nd, b1, W2, h2, N, swiz);
    gg_kernel<<<N / GGN, 256, 0, stream>>>(
        h2, ssrc, rowptr, ns, nd, b2, W3, hF, N, swiz);
    gather_kernel<<<N / 32, 256, 0, stream>>>(
        hF, ssrc, rowptr, agg, nd, b3, N, swiz);
}